// Round 5
// baseline (1951.757 us; speedup 1.0000x reference)
//
#include <hip/hip_runtime.h>
#include <hip/hip_bf16.h>
#include <stdint.h>
#include <math.h>

#define NUM_FF 7
#define DM 512
#define RD 128
#define VOCABN 128
#define BATCH 128
#define TLEN 1024

typedef unsigned int u32x4 __attribute__((ext_vector_type(4)));

// ---- pack ff into per-thread-contiguous chunks:
// ffq[(l*4+q)*DM*4 + j*4 + k] bit i = (ff[l][32*(q*4+k)+i][j] > 0)
// so thread j's 16B chunk for (layer l, quarter q) is one dwordx4. ----
__global__ void pack_ff_kernel(const float* __restrict__ ff, uint32_t* __restrict__ ffq) {
    int idx = blockIdx.x * blockDim.x + threadIdx.x;
    if (idx >= NUM_FF * 16 * DM) return;
    int j = idx & (DM - 1);
    int m = (idx >> 9) & 15;   // word index 0..15
    int l = idx >> 13;
    const float* base = ff + (size_t)l * DM * DM + (size_t)(m * 32) * DM + j;
    uint32_t w = 0;
#pragma unroll
    for (int i = 0; i < 32; ++i)
        w |= (base[(size_t)i * DM] > 0.0f ? 1u : 0u) << i;
    ffq[(l * 4 + (m >> 2)) * DM * 4 + j * 4 + (m & 3)] = w;
}

// ---- integer thresholds: bit = (512-2a >= th)  <=>  a <= floor((512-th)/2) ----
__global__ void pack_thresh_kernel(const float* __restrict__ th, int* __restrict__ it) {
    int idx = blockIdx.x * blockDim.x + threadIdx.x;
    if (idx < NUM_FF * DM)
        it[idx] = (int)floor((512.0 - (double)th[idx]) * 0.5);
}

// ---- pack embed/head/initial (512 threads, 1 block) ----
__global__ void pack_small_kernel(const float* __restrict__ embed,
                                  const float* __restrict__ head,
                                  const float* __restrict__ initial,
                                  uint32_t* __restrict__ embp,
                                  uint32_t* __restrict__ headp,
                                  uint32_t* __restrict__ initp) {
    int idx = threadIdx.x; // 512
    {   // embp[v*4+k] bit i = embed[v][32k+i] > 0
        int v = idx >> 2, k = idx & 3;
        uint32_t w = 0;
#pragma unroll
        for (int i = 0; i < 32; ++i)
            w |= (embed[v * RD + k * 32 + i] > 0.0f ? 1u : 0u) << i;
        embp[idx] = w;
    }
    {   // headp[k*128+v] bit i = head[32k+i][v] > 0
        int k = idx >> 7, v = idx & 127;
        uint32_t w = 0;
#pragma unroll
        for (int i = 0; i < 32; ++i)
            w |= (head[(k * 32 + i) * VOCABN + v] > 0.0f ? 1u : 0u) << i;
        headp[idx] = w;
    }
    if (idx < 16) {
        uint32_t w = 0;
#pragma unroll
        for (int i = 0; i < 32; ++i)
            w |= (initial[idx * 32 + i] > 0.0f ? 1u : 0u) << i;
        initp[idx] = w;
    }
}

__device__ __forceinline__ int bdot4(uint4 s0, uint4 s1, uint4 s2, uint4 s3,
                                     u32x4 w0, u32x4 w1, u32x4 w2, u32x4 w3) {
    int a = __popc(s0.x ^ w0[0]);
    a += __popc(s0.y ^ w0[1]);
    a += __popc(s0.z ^ w0[2]);
    a += __popc(s0.w ^ w0[3]);
    a += __popc(s1.x ^ w1[0]);
    a += __popc(s1.y ^ w1[1]);
    a += __popc(s1.z ^ w1[2]);
    a += __popc(s1.w ^ w1[3]);
    int c = __popc(s2.x ^ w2[0]);
    c += __popc(s2.y ^ w2[1]);
    c += __popc(s2.z ^ w2[2]);
    c += __popc(s2.w ^ w2[3]);
    c += __popc(s3.x ^ w3[0]);
    c += __popc(s3.y ^ w3[1]);
    c += __popc(s3.z ^ w3[2]);
    c += __popc(s3.w ^ w3[3]);
    return a + c;
}

// LDS-visibility barrier WITHOUT draining vmcnt (global logit stores stay in flight)
#define SYNCB asm volatile("s_waitcnt lgkmcnt(0)\n\ts_barrier" ::: "memory")

// ---- main persistent RNN kernel: 1 workgroup (512 thr, 8 waves) per chain ----
__launch_bounds__(512, 2)
__global__ void brnn_kernel(const int* __restrict__ tokens,
                            const uint32_t* __restrict__ ffq,
                            const int* __restrict__ ithr,
                            const uint32_t* __restrict__ embp,
                            const uint32_t* __restrict__ headp,
                            const uint32_t* __restrict__ initp,
                            float* __restrict__ out) {
    const int b = blockIdx.x;
    const int tid = threadIdx.x;      // == output column for this thread
    const int wv = tid >> 6;
    const int lane = tid & 63;

    __shared__ uint4 xq0[4], xq1[4];  // double-buffered 512-bit state
    __shared__ uint4 hx4;             // layer-6 read-slice words for head
    __shared__ uint32_t emb_lds[DM];  // 128 vocab x 4 words
    __shared__ int tok_lds[TLEN + 2];

    // per-thread weights: column `tid`, 7 layers x 4 u32x4 chunks, loaded by
    // INLINE-ASM global_load_dwordx4 into NAMED registers. Asm results are
    // opaque SSA values with no memory home: the compiler cannot sink, remat,
    // or scratch-home them (the round-1..4 failure: weights streamed through
    // L1/L2 every layer, ~1.3 GB FETCH, ~650cyc/layer L2-bound).
    u32x4 W00, W01, W02, W03, W10, W11, W12, W13, W20, W21, W22, W23,
          W30, W31, W32, W33, W40, W41, W42, W43, W50, W51, W52, W53,
          W60, W61, W62, W63;
#define WLOAD(V, L, Q) asm volatile("global_load_dwordx4 %0, %1, off" \
        : "=v"(V) : "v"(ffq + ((L) * 4 + (Q)) * (DM * 4) + tid * 4))
    WLOAD(W00, 0, 0); WLOAD(W01, 0, 1); WLOAD(W02, 0, 2); WLOAD(W03, 0, 3);
    WLOAD(W10, 1, 0); WLOAD(W11, 1, 1); WLOAD(W12, 1, 2); WLOAD(W13, 1, 3);
    WLOAD(W20, 2, 0); WLOAD(W21, 2, 1); WLOAD(W22, 2, 2); WLOAD(W23, 2, 3);
    WLOAD(W30, 3, 0); WLOAD(W31, 3, 1); WLOAD(W32, 3, 2); WLOAD(W33, 3, 3);
    WLOAD(W40, 4, 0); WLOAD(W41, 4, 1); WLOAD(W42, 4, 2); WLOAD(W43, 4, 3);
    WLOAD(W50, 5, 0); WLOAD(W51, 5, 1); WLOAD(W52, 5, 2); WLOAD(W53, 5, 3);
    WLOAD(W60, 6, 0); WLOAD(W61, 6, 1); WLOAD(W62, 6, 2); WLOAD(W63, 6, 3);
#undef WLOAD
    asm volatile("s_waitcnt vmcnt(0)" ::: "memory");

    const int it0 = ithr[0 * DM + tid];
    const int it1 = ithr[1 * DM + tid];
    const int it2 = ithr[2 * DM + tid];
    const int it3 = ithr[3 * DM + tid];
    const int it4 = ithr[4 * DM + tid];
    const int it5 = ithr[5 * DM + tid];
    const int it6 = ithr[6 * DM + tid];

    // head weights: vocab v = 16*wv + (lane&15), used by lanes 0..15 of each wave
    const int hvv = (wv << 4) | (lane & 15);
    const uint32_t h0 = headp[0 * VOCABN + hvv];
    const uint32_t h1 = headp[1 * VOCABN + hvv];
    const uint32_t h2 = headp[2 * VOCABN + hvv];
    const uint32_t h3 = headp[3 * VOCABN + hvv];

    emb_lds[tid] = embp[tid];
    tok_lds[tid] = tokens[b * TLEN + tid];
    tok_lds[tid + 512] = tokens[b * TLEN + tid + 512];
    if (tid == 0) { tok_lds[TLEN] = 0; tok_lds[TLEN + 1] = 0; }
    if (tid < 16) ((uint32_t*)xq0)[tid] = initp[tid];
    __syncthreads();
    if (tid < 4) ((uint32_t*)xq0)[12 + tid] = emb_lds[tok_lds[0] * 4 + tid];
    __syncthreads();

    float* outb = out + (size_t)b * TLEN * VOCABN;

#define LAYER(L, SRCQ, DSTQ) do {                                              \
        const uint4* xb_ = (const uint4*)(SRCQ);                               \
        uint4 s0 = xb_[0], s1 = xb_[1], s2 = xb_[2], s3 = xb_[3];              \
        int acc = bdot4(s0, s1, s2, s3, W##L##0, W##L##1, W##L##2, W##L##3);   \
        unsigned long long m = __ballot(acc <= it##L);                         \
        if (lane == 0)                                                         \
            ((uint2*)(DSTQ))[wv] = make_uint2((uint32_t)m, (uint32_t)(m >> 32)); \
        SYNCB;                                                                 \
    } while (0)

#define LAYERF(SRCQ, DSTQ) do {                                                \
        const uint4* xb_ = (const uint4*)(SRCQ);                               \
        uint4 s0 = xb_[0], s1 = xb_[1], s2 = xb_[2], s3 = xb_[3];              \
        int acc = bdot4(s0, s1, s2, s3, W60, W61, W62, W63);                   \
        unsigned long long m = __ballot(acc <= it6);                           \
        if (lane == 0) {                                                       \
            uint2 v_ = make_uint2((uint32_t)m, (uint32_t)(m >> 32));           \
            if (wv < 6) ((uint2*)(DSTQ))[wv] = v_;                             \
            else ((uint2*)&hx4)[wv - 6] = v_;                                  \
        }                                                                      \
        if (wv == 7 && lane < 4) ((uint32_t*)(DSTQ))[12 + lane] = embw;        \
        SYNCB;                                                                 \
    } while (0)

#define STEP(AQ, BQ, T) do {                                                   \
        /* prefetch next token's embedding early (wave 7 only) */              \
        uint32_t embw = 0;                                                     \
        if (wv == 7) embw = emb_lds[tok_lds[(T) + 1] * 4 + (lane & 3)];        \
        LAYER(0, AQ, BQ);                                                      \
        LAYER(1, BQ, AQ);                                                      \
        LAYER(2, AQ, BQ);                                                      \
        LAYER(3, BQ, AQ);                                                      \
        LAYER(4, AQ, BQ);                                                      \
        LAYER(5, BQ, AQ);                                                      \
        LAYERF(AQ, BQ);                                                        \
        uint4 hv_ = hx4;                                                       \
        if (lane < 16) {                                                       \
            int hc = __popc(hv_.x ^ h0) + __popc(hv_.y ^ h1) +                 \
                     __popc(hv_.z ^ h2) + __popc(hv_.w ^ h3);                  \
            outb[(T) * VOCABN + hvv] = (float)(RD - 2 * hc);                   \
        }                                                                      \
    } while (0)

    for (int t = 0; t < TLEN; t += 2) {
        STEP(xq0, xq1, t);
        STEP(xq1, xq0, t + 1);
    }
#undef LAYER
#undef LAYERF
#undef STEP
}

extern "C" void kernel_launch(void* const* d_in, const int* in_sizes, int n_in,
                              void* d_out, int out_size, void* d_ws, size_t ws_size,
                              hipStream_t stream) {
    const int* tokens = (const int*)d_in[0];
    const float* initial = (const float*)d_in[1];
    const float* embed = (const float*)d_in[2];
    const float* ff = (const float*)d_in[3];
    const float* ff_thresh = (const float*)d_in[4];
    const float* head = (const float*)d_in[5];
    float* out = (float*)d_out;

    uint32_t* ffq = (uint32_t*)d_ws;              // 7*16*512 = 57344 words (16B-aligned chunks)
    uint32_t* embp = ffq + NUM_FF * 16 * DM;      // 512 words
    uint32_t* headp = embp + 512;                 // 512 words
    uint32_t* initp = headp + 512;                // 16 words
    int* ithr = (int*)(initp + 16);               // 7*512 ints

    pack_ff_kernel<<<(NUM_FF * 16 * DM + 255) / 256, 256, 0, stream>>>(ff, ffq);
    pack_thresh_kernel<<<(NUM_FF * DM + 255) / 256, 256, 0, stream>>>(ff_thresh, ithr);
    pack_small_kernel<<<1, 512, 0, stream>>>(embed, head, initial, embp, headp, initp);
    brnn_kernel<<<BATCH, 512, 0, stream>>>(tokens, ffq, ithr, embp, headp, initp, out);
}

// Round 6
// 1945.602 us; speedup vs baseline: 1.0032x; 1.0032x over previous
//
#include <hip/hip_runtime.h>
#include <hip/hip_bf16.h>
#include <stdint.h>
#include <math.h>

#define NUM_FF 7
#define DM 512
#define RD 128
#define VOCABN 128
#define BATCH 128
#define TLEN 1024

typedef unsigned int u32x4 __attribute__((ext_vector_type(4)));

// ---- pack ff into per-thread-contiguous chunks:
// ffq[(l*4+q)*DM*4 + j*4 + k] bit i = (ff[l][32*(q*4+k)+i][j] > 0)
// so thread j's 16B chunk for (layer l, quarter q) is one dwordx4. ----
__global__ void pack_ff_kernel(const float* __restrict__ ff, uint32_t* __restrict__ ffq) {
    int idx = blockIdx.x * blockDim.x + threadIdx.x;
    if (idx >= NUM_FF * 16 * DM) return;
    int j = idx & (DM - 1);
    int m = (idx >> 9) & 15;   // word index 0..15
    int l = idx >> 13;
    const float* base = ff + (size_t)l * DM * DM + (size_t)(m * 32) * DM + j;
    uint32_t w = 0;
#pragma unroll
    for (int i = 0; i < 32; ++i)
        w |= (base[(size_t)i * DM] > 0.0f ? 1u : 0u) << i;
    ffq[(l * 4 + (m >> 2)) * DM * 4 + j * 4 + (m & 3)] = w;
}

// ---- integer thresholds: bit = (512-2a >= th)  <=>  a <= floor((512-th)/2) ----
__global__ void pack_thresh_kernel(const float* __restrict__ th, int* __restrict__ it) {
    int idx = blockIdx.x * blockDim.x + threadIdx.x;
    if (idx < NUM_FF * DM)
        it[idx] = (int)floor((512.0 - (double)th[idx]) * 0.5);
}

// ---- pack embed/head/initial (512 threads, 1 block) ----
__global__ void pack_small_kernel(const float* __restrict__ embed,
                                  const float* __restrict__ head,
                                  const float* __restrict__ initial,
                                  uint32_t* __restrict__ embp,
                                  uint32_t* __restrict__ headp,
                                  uint32_t* __restrict__ initp) {
    int idx = threadIdx.x; // 512
    {   // embp[v*4+k] bit i = embed[v][32k+i] > 0
        int v = idx >> 2, k = idx & 3;
        uint32_t w = 0;
#pragma unroll
        for (int i = 0; i < 32; ++i)
            w |= (embed[v * RD + k * 32 + i] > 0.0f ? 1u : 0u) << i;
        embp[idx] = w;
    }
    {   // headp[k*128+v] bit i = head[32k+i][v] > 0
        int k = idx >> 7, v = idx & 127;
        uint32_t w = 0;
#pragma unroll
        for (int i = 0; i < 32; ++i)
            w |= (head[(k * 32 + i) * VOCABN + v] > 0.0f ? 1u : 0u) << i;
        headp[idx] = w;
    }
    if (idx < 16) {
        uint32_t w = 0;
#pragma unroll
        for (int i = 0; i < 32; ++i)
            w |= (initial[idx * 32 + i] > 0.0f ? 1u : 0u) << i;
        initp[idx] = w;
    }
}

__device__ __forceinline__ int bdot4(uint4 s0, uint4 s1, uint4 s2, uint4 s3,
                                     u32x4 w0, u32x4 w1, u32x4 w2, u32x4 w3) {
    int a = __popc(s0.x ^ w0[0]);
    a += __popc(s0.y ^ w0[1]);
    a += __popc(s0.z ^ w0[2]);
    a += __popc(s0.w ^ w0[3]);
    a += __popc(s1.x ^ w1[0]);
    a += __popc(s1.y ^ w1[1]);
    a += __popc(s1.z ^ w1[2]);
    a += __popc(s1.w ^ w1[3]);
    int c = __popc(s2.x ^ w2[0]);
    c += __popc(s2.y ^ w2[1]);
    c += __popc(s2.z ^ w2[2]);
    c += __popc(s2.w ^ w2[3]);
    c += __popc(s3.x ^ w3[0]);
    c += __popc(s3.y ^ w3[1]);
    c += __popc(s3.z ^ w3[2]);
    c += __popc(s3.w ^ w3[3]);
    return a + c;
}

// LDS-visibility barrier WITHOUT draining vmcnt (global logit stores stay in flight)
#define SYNCB asm volatile("s_waitcnt lgkmcnt(0)\n\ts_barrier" ::: "memory")

// ---- main persistent RNN kernel: 1 workgroup (512 thr, 8 waves) per chain ----
// amdgpu_waves_per_eu(2,2) pins the scheduler's occupancy TARGET to exactly 2
// waves/EU (register budget 256). Rounds 1-5 failure mode: launch_bounds' 2nd
// arg is only a MINIMUM; the backend targeted ~8 waves/EU (VGPR~76) and made
// the weights memory-resident (sunk loads / scratch spills) -> 1.28 GB/dispatch
// FETCH of weight re-reads, ~650 cyc/layer L2-bound. Occupancy is structurally
// grid-limited (128 blocks) so the "extra occupancy" bought nothing.
__attribute__((amdgpu_waves_per_eu(2, 2)))
__launch_bounds__(512, 2)
__global__ void brnn_kernel(const int* __restrict__ tokens,
                            const uint32_t* __restrict__ ffq,
                            const int* __restrict__ ithr,
                            const uint32_t* __restrict__ embp,
                            const uint32_t* __restrict__ headp,
                            const uint32_t* __restrict__ initp,
                            float* __restrict__ out) {
    const int b = blockIdx.x;
    const int tid = threadIdx.x;      // == output column for this thread
    const int wv = tid >> 6;
    const int lane = tid & 63;

    __shared__ uint4 xq0[4], xq1[4];  // double-buffered 512-bit state
    __shared__ uint4 hx4;             // layer-6 read-slice words for head
    __shared__ uint32_t emb_lds[DM];  // 128 vocab x 4 words
    __shared__ int tok_lds[TLEN + 2];

    // per-thread weights: column `tid`, 7 layers x 4 u32x4 chunks, loaded by
    // INLINE-ASM global_load_dwordx4 into NAMED registers (unsinkable), kept
    // resident by the waves_per_eu(2,2) register budget (no spill incentive).
    u32x4 W00, W01, W02, W03, W10, W11, W12, W13, W20, W21, W22, W23,
          W30, W31, W32, W33, W40, W41, W42, W43, W50, W51, W52, W53,
          W60, W61, W62, W63;
#define WLOAD(V, L, Q) asm volatile("global_load_dwordx4 %0, %1, off" \
        : "=v"(V) : "v"(ffq + ((L) * 4 + (Q)) * (DM * 4) + tid * 4))
    WLOAD(W00, 0, 0); WLOAD(W01, 0, 1); WLOAD(W02, 0, 2); WLOAD(W03, 0, 3);
    WLOAD(W10, 1, 0); WLOAD(W11, 1, 1); WLOAD(W12, 1, 2); WLOAD(W13, 1, 3);
    WLOAD(W20, 2, 0); WLOAD(W21, 2, 1); WLOAD(W22, 2, 2); WLOAD(W23, 2, 3);
    WLOAD(W30, 3, 0); WLOAD(W31, 3, 1); WLOAD(W32, 3, 2); WLOAD(W33, 3, 3);
    WLOAD(W40, 4, 0); WLOAD(W41, 4, 1); WLOAD(W42, 4, 2); WLOAD(W43, 4, 3);
    WLOAD(W50, 5, 0); WLOAD(W51, 5, 1); WLOAD(W52, 5, 2); WLOAD(W53, 5, 3);
    WLOAD(W60, 6, 0); WLOAD(W61, 6, 1); WLOAD(W62, 6, 2); WLOAD(W63, 6, 3);
#undef WLOAD
    asm volatile("s_waitcnt vmcnt(0)" ::: "memory");

    const int it0 = ithr[0 * DM + tid];
    const int it1 = ithr[1 * DM + tid];
    const int it2 = ithr[2 * DM + tid];
    const int it3 = ithr[3 * DM + tid];
    const int it4 = ithr[4 * DM + tid];
    const int it5 = ithr[5 * DM + tid];
    const int it6 = ithr[6 * DM + tid];

    // head weights: vocab v = 16*wv + (lane&15), used by lanes 0..15 of each wave
    const int hvv = (wv << 4) | (lane & 15);
    const uint32_t h0 = headp[0 * VOCABN + hvv];
    const uint32_t h1 = headp[1 * VOCABN + hvv];
    const uint32_t h2 = headp[2 * VOCABN + hvv];
    const uint32_t h3 = headp[3 * VOCABN + hvv];

    emb_lds[tid] = embp[tid];
    tok_lds[tid] = tokens[b * TLEN + tid];
    tok_lds[tid + 512] = tokens[b * TLEN + tid + 512];
    if (tid == 0) { tok_lds[TLEN] = 0; tok_lds[TLEN + 1] = 0; }
    if (tid < 16) ((uint32_t*)xq0)[tid] = initp[tid];
    __syncthreads();
    if (tid < 4) ((uint32_t*)xq0)[12 + tid] = emb_lds[tok_lds[0] * 4 + tid];
    __syncthreads();

    float* outb = out + (size_t)b * TLEN * VOCABN;

#define LAYER(L, SRCQ, DSTQ) do {                                              \
        const uint4* xb_ = (const uint4*)(SRCQ);                               \
        uint4 s0 = xb_[0], s1 = xb_[1], s2 = xb_[2], s3 = xb_[3];              \
        int acc = bdot4(s0, s1, s2, s3, W##L##0, W##L##1, W##L##2, W##L##3);   \
        unsigned long long m = __ballot(acc <= it##L);                         \
        if (lane == 0)                                                         \
            ((uint2*)(DSTQ))[wv] = make_uint2((uint32_t)m, (uint32_t)(m >> 32)); \
        SYNCB;                                                                 \
    } while (0)

#define LAYERF(SRCQ, DSTQ) do {                                                \
        const uint4* xb_ = (const uint4*)(SRCQ);                               \
        uint4 s0 = xb_[0], s1 = xb_[1], s2 = xb_[2], s3 = xb_[3];              \
        int acc = bdot4(s0, s1, s2, s3, W60, W61, W62, W63);                   \
        unsigned long long m = __ballot(acc <= it6);                           \
        if (lane == 0) {                                                       \
            uint2 v_ = make_uint2((uint32_t)m, (uint32_t)(m >> 32));           \
            if (wv < 6) ((uint2*)(DSTQ))[wv] = v_;                             \
            else ((uint2*)&hx4)[wv - 6] = v_;                                  \
        }                                                                      \
        if (wv == 7 && lane < 4) ((uint32_t*)(DSTQ))[12 + lane] = embw;        \
        SYNCB;                                                                 \
    } while (0)

#define STEP(AQ, BQ, T) do {                                                   \
        /* prefetch next token's embedding early (wave 7 only) */              \
        uint32_t embw = 0;                                                     \
        if (wv == 7) embw = emb_lds[tok_lds[(T) + 1] * 4 + (lane & 3)];        \
        LAYER(0, AQ, BQ);                                                      \
        LAYER(1, BQ, AQ);                                                      \
        LAYER(2, AQ, BQ);                                                      \
        LAYER(3, BQ, AQ);                                                      \
        LAYER(4, AQ, BQ);                                                      \
        LAYER(5, BQ, AQ);                                                      \
        LAYERF(AQ, BQ);                                                        \
        uint4 hv_ = hx4;                                                       \
        if (lane < 16) {                                                       \
            int hc = __popc(hv_.x ^ h0) + __popc(hv_.y ^ h1) +                 \
                     __popc(hv_.z ^ h2) + __popc(hv_.w ^ h3);                  \
            outb[(T) * VOCABN + hvv] = (float)(RD - 2 * hc);                   \
        }                                                                      \
    } while (0)

    for (int t = 0; t < TLEN; t += 2) {
        STEP(xq0, xq1, t);
        STEP(xq1, xq0, t + 1);
    }
#undef LAYER
#undef LAYERF
#undef STEP
}

extern "C" void kernel_launch(void* const* d_in, const int* in_sizes, int n_in,
                              void* d_out, int out_size, void* d_ws, size_t ws_size,
                              hipStream_t stream) {
    const int* tokens = (const int*)d_in[0];
    const float* initial = (const float*)d_in[1];
    const float* embed = (const float*)d_in[2];
    const float* ff = (const float*)d_in[3];
    const float* ff_thresh = (const float*)d_in[4];
    const float* head = (const float*)d_in[5];
    float* out = (float*)d_out;

    uint32_t* ffq = (uint32_t*)d_ws;              // 7*16*512 = 57344 words (16B-aligned chunks)
    uint32_t* embp = ffq + NUM_FF * 16 * DM;      // 512 words
    uint32_t* headp = embp + 512;                 // 512 words
    uint32_t* initp = headp + 512;                // 16 words
    int* ithr = (int*)(initp + 16);               // 7*512 ints

    pack_ff_kernel<<<(NUM_FF * 16 * DM + 255) / 256, 256, 0, stream>>>(ff, ffq);
    pack_thresh_kernel<<<(NUM_FF * DM + 255) / 256, 256, 0, stream>>>(ff_thresh, ithr);
    pack_small_kernel<<<1, 512, 0, stream>>>(embed, head, initial, embp, headp, initp);
    brnn_kernel<<<BATCH, 512, 0, stream>>>(tokens, ffq, ithr, embp, headp, initp, out);
}